// Round 1
// baseline (485.588 us; speedup 1.0000x reference)
//
#include <hip/hip_runtime.h>

// RecurrentResonanceModel on MI355X.
// Pipeline: k_sel_mom -> k_transpose (atoms fp32 [A][S] -> bf16 [S][A]) ->
//           k_gemm (res[m][s] = sel[m][:] . atoms[:][s], bf16 MFMA) ->
//           k_final (frame norms + hann + momentum scale + overlap-add).
//
// Sizes: M=1024 (B*E), L=128, A=1024, S=32768, F=128, W=512, HOP=256.
// d_out = [ out (1024*32768 f32) | mom (1024*128 f32) ]
// d_ws  = [ atomsT bf16 67108864 B | sel bf16 2097152 B | res bf16 67108864 B ]

typedef __attribute__((ext_vector_type(8))) short short8;
typedef __attribute__((ext_vector_type(4))) float f32x4;

typedef __attribute__((address_space(1))) void GV;
typedef __attribute__((address_space(3))) void LV;

__device__ __forceinline__ unsigned short f2bf(float f) {
    union { float f; unsigned u; } c; c.f = f;
    unsigned u = c.u;
    u = (u + 0x7FFFu + ((u >> 16) & 1u)) >> 16;   // RNE
    return (unsigned short)u;
}
__device__ __forceinline__ float bf2f(unsigned short h) {
    union { unsigned u; float f; } c; c.u = ((unsigned)h) << 16; return c.f;
}

// ---------------------------------------------------------------- kernel 1
// One workgroup per (b,e) row: softmax atom selection (bf16 out) + momentum
// cumprod (fp32 straight to d_out's second output region).
__global__ __launch_bounds__(256) void k_sel_mom(
        const float* __restrict__ x, const float* __restrict__ Wsel,
        const float* __restrict__ bsel, const float* __restrict__ Wmom,
        const float* __restrict__ bmom, unsigned short* __restrict__ sel,
        float* __restrict__ momout) {
    __shared__ float xs[128];
    __shared__ float logits[1024];
    __shared__ float mvals[128];
    __shared__ float wred[4];
    __shared__ float sstat[2];
    const int tid = threadIdx.x;
    const int m = blockIdx.x;

    if (tid < 32) *(float4*)&xs[tid * 4] = *(const float4*)(x + (size_t)m * 128 + tid * 4);
    __syncthreads();

    for (int a = tid; a < 1024; a += 256) {
        const float4* w = (const float4*)(Wsel + (size_t)a * 128);
        float acc = 0.f;
#pragma unroll
        for (int k = 0; k < 32; ++k) {
            float4 wv = w[k]; float4 xv = *(const float4*)&xs[k * 4];
            acc += wv.x * xv.x + wv.y * xv.y + wv.z * xv.z + wv.w * xv.w;
        }
        logits[a] = acc + bsel[a];
    }
    if (tid < 128) {
        const float4* w = (const float4*)(Wmom + (size_t)tid * 128);
        float acc = 0.f;
#pragma unroll
        for (int k = 0; k < 32; ++k) {
            float4 wv = w[k]; float4 xv = *(const float4*)&xs[k * 4];
            acc += wv.x * xv.x + wv.y * xv.y + wv.z * xv.z + wv.w * xv.w;
        }
        acc += bmom[tid];
        float sig = 1.f / (1.f + __expf(-acc));
        mvals[tid] = 0.2f + sig * 0.72f;      // BASE_RES + sigmoid*RES_FACTOR
    }
    __syncthreads();

    // row max
    float mx = -1e30f;
    for (int a = tid; a < 1024; a += 256) mx = fmaxf(mx, logits[a]);
#pragma unroll
    for (int off = 32; off; off >>= 1) mx = fmaxf(mx, __shfl_xor(mx, off, 64));
    if ((tid & 63) == 0) wred[tid >> 6] = mx;
    __syncthreads();
    if (tid == 0) sstat[0] = fmaxf(fmaxf(wred[0], wred[1]), fmaxf(wred[2], wred[3]));
    __syncthreads();
    mx = sstat[0];

    // exp + sum
    float psum = 0.f;
    for (int a = tid; a < 1024; a += 256) {
        float e = __expf(logits[a] - mx);
        logits[a] = e;
        psum += e;
    }
#pragma unroll
    for (int off = 32; off; off >>= 1) psum += __shfl_xor(psum, off, 64);
    if ((tid & 63) == 0) wred[tid >> 6] = psum;
    __syncthreads();
    if (tid == 0) sstat[1] = wred[0] + wred[1] + wred[2] + wred[3];
    __syncthreads();
    const float inv = 1.f / sstat[1];
    for (int a = tid; a < 1024; a += 256)
        sel[(size_t)m * 1024 + a] = f2bf(logits[a] * inv);

    // momentum cumprod (serial: 128 iters, trivial)
    if (tid == 0) {
        float p = 1.f;
        for (int f = 0; f < 128; ++f) {
            p *= (mvals[f] + 1e-12f);
            momout[(size_t)m * 128 + f] = p;
        }
    }
}

// ---------------------------------------------------------------- kernel 2
// atoms fp32 [1024][32768] -> atomsT bf16 [32768][1024] via 64x64 LDS tile.
__global__ __launch_bounds__(256) void k_transpose(
        const float* __restrict__ atoms, unsigned short* __restrict__ atomsT) {
    __shared__ float t[64][65];
    const int tid = threadIdx.x;
    const int s0 = blockIdx.x * 64;
    const int a0 = blockIdx.y * 64;

    {
        const int r0 = tid >> 4;          // 0..15
        const int c4 = (tid & 15) * 4;    // 0..60
        for (int rr = r0; rr < 64; rr += 16) {
            float4 v = *(const float4*)(atoms + (size_t)(a0 + rr) * 32768 + s0 + c4);
            t[rr][c4] = v.x; t[rr][c4 + 1] = v.y; t[rr][c4 + 2] = v.z; t[rr][c4 + 3] = v.w;
        }
    }
    __syncthreads();
    {
        const int sl = tid >> 2;            // 0..63  (sample within tile)
        const int seg = (tid & 3) * 16;     // 0,16,32,48 (atom chunk)
        unsigned short* dst = atomsT + (size_t)(s0 + sl) * 1024 + a0 + seg;
        unsigned pk[8];
#pragma unroll
        for (int i = 0; i < 16; i += 2) {
            unsigned short h0 = f2bf(t[seg + i][sl]);
            unsigned short h1 = f2bf(t[seg + i + 1][sl]);
            pk[i >> 1] = (unsigned)h0 | ((unsigned)h1 << 16);
        }
        uint4 q0; q0.x = pk[0]; q0.y = pk[1]; q0.z = pk[2]; q0.w = pk[3];
        uint4 q1; q1.x = pk[4]; q1.y = pk[5]; q1.z = pk[6]; q1.w = pk[7];
        *(uint4*)(dst) = q0;
        *(uint4*)(dst + 8) = q1;
    }
}

// ---------------------------------------------------------------- kernel 3
// res[m][s] = sum_a sel[m][a] * atomsT[s][a].  m97-style gemm_bt:
// A = atomsT [32768][1024] bf16, B = sel [1024][1024] bf16, both K-contig.
// 128x128 tile, BK=32, global_load_lds width-16 staging, 16x16x32 MFMA.
__global__ __launch_bounds__(256) void k_gemm(
        const unsigned short* __restrict__ A, const unsigned short* __restrict__ Bm,
        unsigned short* __restrict__ res) {
    __shared__ __align__(16) unsigned short lA[128 * 32];
    __shared__ __align__(16) unsigned short lB[128 * 32];
    const int tid = threadIdx.x;
    const int wave = tid >> 6;
    const int lane = tid & 63;
    const int l15 = lane & 15, quad = lane >> 4;
    const int j0 = blockIdx.x * 128;   // m (sel rows)
    const int i0 = blockIdx.y * 128;   // s (atomsT rows)
    const int wi = wave >> 1, wj = wave & 1;
    const int rsel = lane >> 2;        // 0..15 row within 16-row stripe
    const int koff = (lane & 3) * 8;   // ushort offset within 32-wide K tile

    f32x4 acc[4][4] = {};

    for (int kt = 0; kt < 32; ++kt) {
        const int kbase = kt * 32;
#pragma unroll
        for (int c = 0; c < 2; ++c) {
            const int row = c * 64 + wave * 16 + rsel;
            const unsigned short* ga = A + (size_t)(i0 + row) * 1024 + kbase + koff;
            const unsigned short* gb = Bm + (size_t)(j0 + row) * 1024 + kbase + koff;
            unsigned short* la = lA + (c * 64 + wave * 16) * 32;  // wave-uniform base
            unsigned short* lb = lB + (c * 64 + wave * 16) * 32;
            __builtin_amdgcn_global_load_lds((GV*)ga, (LV*)la, 16, 0, 0);
            __builtin_amdgcn_global_load_lds((GV*)gb, (LV*)lb, 16, 0, 0);
        }
        __syncthreads();

        short8 af[4], bf[4];
#pragma unroll
        for (int ti = 0; ti < 4; ++ti)
            af[ti] = *(const short8*)(lA + (wi * 64 + ti * 16 + l15) * 32 + quad * 8);
#pragma unroll
        for (int tj = 0; tj < 4; ++tj)
            bf[tj] = *(const short8*)(lB + (wj * 64 + tj * 16 + l15) * 32 + quad * 8);
#pragma unroll
        for (int ti = 0; ti < 4; ++ti)
#pragma unroll
            for (int tj = 0; tj < 4; ++tj)
                acc[ti][tj] = __builtin_amdgcn_mfma_f32_16x16x32_bf16(
                    af[ti], bf[tj], acc[ti][tj], 0, 0, 0);
        __syncthreads();
    }

    // Epilogue: C/D layout col=lane&15 (m), row=quad*4+reg (s). 4 consecutive
    // s per lane -> 8 B bf16 store.
#pragma unroll
    for (int ti = 0; ti < 4; ++ti) {
#pragma unroll
        for (int tj = 0; tj < 4; ++tj) {
            const int mrow = j0 + wj * 64 + tj * 16 + l15;
            const int sbase = i0 + wi * 64 + ti * 16 + quad * 4;
            f32x4 v = acc[ti][tj];
            uint2 q;
            q.x = (unsigned)f2bf(v[0]) | ((unsigned)f2bf(v[1]) << 16);
            q.y = (unsigned)f2bf(v[2]) | ((unsigned)f2bf(v[3]) << 16);
            *(uint2*)(res + (size_t)mrow * 32768 + sbase) = q;
        }
    }
}

// ---------------------------------------------------------------- kernel 4
// Per row: stage res row (bf16, 64 KB LDS), 128 frame norms (wave reduce),
// scale = mom/(norm+1e-8), out[s] = res[s]*(hann[i1]*sc[f1]+hann[i1+256]*sc[f1-1]).
__global__ __launch_bounds__(256) void k_final(
        const unsigned short* __restrict__ res, const float* __restrict__ mom,
        float* __restrict__ out) {
    __shared__ __align__(16) unsigned short row[32768];
    __shared__ float hann[512];
    __shared__ float scale[128];
    const int tid = threadIdx.x;
    const int m = blockIdx.x;

#pragma unroll
    for (int j = 0; j < 16; ++j)
        *(uint4*)(row + j * 2048 + tid * 8) =
            *(const uint4*)(res + (size_t)m * 32768 + j * 2048 + tid * 8);
    for (int i = tid; i < 512; i += 256)
        hann[i] = 0.5f * (1.f - cosf(6.283185307179586f * (float)i / 512.f));
    __syncthreads();

    const int wave = tid >> 6, lane = tid & 63;
    for (int f = wave; f < 128; f += 4) {
        float s = 0.f;
#pragma unroll
        for (int jj = 0; jj < 8; ++jj) {
            const int i = jj * 64 + lane;
            const int idx = f * 256 + i;
            float v = (idx < 32768) ? bf2f(row[idx]) : 0.f;   // zero pad tail
            float wv = v * hann[i];
            s += wv * wv;
        }
#pragma unroll
        for (int off = 32; off; off >>= 1) s += __shfl_xor(s, off, 64);
        if (lane == 0) scale[f] = mom[(size_t)m * 128 + f] / (sqrtf(s) + 1e-8f);
    }
    __syncthreads();

#pragma unroll 4
    for (int j = 0; j < 32; ++j) {
        const int s0 = j * 1024 + tid * 4;
        const int f1 = s0 >> 8, i1 = s0 & 255;
        const float sc1 = scale[f1];
        const float sc0 = f1 ? scale[f1 - 1] : 0.f;
        float4 o;
        o.x = bf2f(row[s0])     * (hann[i1]     * sc1 + hann[i1 + 256] * sc0);
        o.y = bf2f(row[s0 + 1]) * (hann[i1 + 1] * sc1 + hann[i1 + 257] * sc0);
        o.z = bf2f(row[s0 + 2]) * (hann[i1 + 2] * sc1 + hann[i1 + 258] * sc0);
        o.w = bf2f(row[s0 + 3]) * (hann[i1 + 3] * sc1 + hann[i1 + 259] * sc0);
        *(float4*)(out + (size_t)m * 32768 + s0) = o;
    }
}

extern "C" void kernel_launch(void* const* d_in, const int* in_sizes, int n_in,
                              void* d_out, int out_size, void* d_ws, size_t ws_size,
                              hipStream_t stream) {
    const float* x     = (const float*)d_in[0];
    const float* Wsel  = (const float*)d_in[1];
    const float* bsel  = (const float*)d_in[2];
    const float* Wmom  = (const float*)d_in[3];
    const float* bmom  = (const float*)d_in[4];
    const float* atoms = (const float*)d_in[5];

    float* out    = (float*)d_out;
    float* momout = out + (size_t)1024 * 32768;   // second output region

    unsigned char* ws = (unsigned char*)d_ws;
    unsigned short* atomsT = (unsigned short*)(ws);                 // 67108864 B
    unsigned short* sel    = (unsigned short*)(ws + 67108864);      //  2097152 B
    unsigned short* res    = (unsigned short*)(ws + 69206016);      // 67108864 B

    k_sel_mom<<<1024, 256, 0, stream>>>(x, Wsel, bsel, Wmom, bmom, sel, momout);
    k_transpose<<<dim3(512, 16), 256, 0, stream>>>(atoms, atomsT);
    k_gemm<<<dim3(8, 256), 256, 0, stream>>>(atomsT, sel, res);
    k_final<<<1024, 256, 0, stream>>>(res, momout, out);
}

// Round 2
// 412.988 us; speedup vs baseline: 1.1758x; 1.1758x over previous
//
#include <hip/hip_runtime.h>

// RecurrentResonanceModel on MI355X.
// Pipeline:
//   k_convert   : x, W_sel fp32 -> bf16
//   k_head_gemm : logits[m][a] = x[m][:] . Wsel[a][:]  (MFMA, f32 out)
//   k_softmax_mom: softmax(logits)+bsel -> sel bf16; mom head fp32 (exact)
//   k_transpose : atoms fp32 [A][S] -> bf16 [S][A]
//   k_gemm      : res[m][s] = sel[m][:] . atomsT[s][:] (MFMA, XCD-swizzled)
//   k_final     : frame norms + hann + momentum scale + overlap-add
//
// Sizes: M=1024 (B*E), L=128, A=1024, S=32768, F=128, W=512, HOP=256.
// d_out = [ out (1024*32768 f32) | mom (1024*128 f32) ]
// d_ws  = [ atomsT bf16 64MB | sel bf16 2MB | res bf16 64MB ]
//         logits f32 (4MB) + xbf (256KB) + wselbf (256KB) live in the res
//         region and are fully consumed before k_gemm overwrites it.

typedef __attribute__((ext_vector_type(8))) short short8;
typedef __attribute__((ext_vector_type(4))) float f32x4;

typedef __attribute__((address_space(1))) void GV;
typedef __attribute__((address_space(3))) void LV;

__device__ __forceinline__ unsigned short f2bf(float f) {
    union { float f; unsigned u; } c; c.f = f;
    unsigned u = c.u;
    u = (u + 0x7FFFu + ((u >> 16) & 1u)) >> 16;   // RNE
    return (unsigned short)u;
}
__device__ __forceinline__ float bf2f(unsigned short h) {
    union { unsigned u; float f; } c; c.u = ((unsigned)h) << 16; return c.f;
}

// ---------------------------------------------------------------- convert
// x (131072 f32) and Wsel (131072 f32) -> bf16. 128 blocks x 256 thr x 4 elem.
__global__ __launch_bounds__(256) void k_convert(
        const float* __restrict__ x, const float* __restrict__ Wsel,
        unsigned short* __restrict__ xbf, unsigned short* __restrict__ wbf) {
    const int i = (blockIdx.x * 256 + threadIdx.x) * 4;
    {
        float4 v = *(const float4*)(x + i);
        uint2 q;
        q.x = (unsigned)f2bf(v.x) | ((unsigned)f2bf(v.y) << 16);
        q.y = (unsigned)f2bf(v.z) | ((unsigned)f2bf(v.w) << 16);
        *(uint2*)(xbf + i) = q;
    }
    {
        float4 v = *(const float4*)(Wsel + i);
        uint2 q;
        q.x = (unsigned)f2bf(v.x) | ((unsigned)f2bf(v.y) << 16);
        q.y = (unsigned)f2bf(v.z) | ((unsigned)f2bf(v.w) << 16);
        *(uint2*)(wbf + i) = q;
    }
}

// ---------------------------------------------------------------- head gemm
// logits[m][a] = sum_k xbf[m][k] * wbf[a][k], K=128. A-op = wbf (rows=a),
// B-op = xbf (rows=m). 128x128 tile, f32 output. grid (8,8).
__global__ __launch_bounds__(256) void k_head_gemm(
        const unsigned short* __restrict__ A, const unsigned short* __restrict__ Bm,
        float* __restrict__ logits) {
    __shared__ __align__(16) unsigned short lA[128 * 32];
    __shared__ __align__(16) unsigned short lB[128 * 32];
    const int tid = threadIdx.x;
    const int wave = tid >> 6;
    const int lane = tid & 63;
    const int l15 = lane & 15, quad = lane >> 4;
    const int i0 = blockIdx.x * 128;   // a (Wsel rows)
    const int j0 = blockIdx.y * 128;   // m (x rows)
    const int wi = wave >> 1, wj = wave & 1;
    const int rsel = lane >> 2;
    const int koff = (lane & 3) * 8;

    f32x4 acc[4][4] = {};

    for (int kt = 0; kt < 4; ++kt) {
        const int kbase = kt * 32;
#pragma unroll
        for (int c = 0; c < 2; ++c) {
            const int row = c * 64 + wave * 16 + rsel;
            const unsigned short* ga = A + (size_t)(i0 + row) * 128 + kbase + koff;
            const unsigned short* gb = Bm + (size_t)(j0 + row) * 128 + kbase + koff;
            unsigned short* la = lA + (c * 64 + wave * 16) * 32;
            unsigned short* lb = lB + (c * 64 + wave * 16) * 32;
            __builtin_amdgcn_global_load_lds((GV*)ga, (LV*)la, 16, 0, 0);
            __builtin_amdgcn_global_load_lds((GV*)gb, (LV*)lb, 16, 0, 0);
        }
        __syncthreads();

        short8 af[4], bf[4];
#pragma unroll
        for (int ti = 0; ti < 4; ++ti)
            af[ti] = *(const short8*)(lA + (wi * 64 + ti * 16 + l15) * 32 + quad * 8);
#pragma unroll
        for (int tj = 0; tj < 4; ++tj)
            bf[tj] = *(const short8*)(lB + (wj * 64 + tj * 16 + l15) * 32 + quad * 8);
#pragma unroll
        for (int ti = 0; ti < 4; ++ti)
#pragma unroll
            for (int tj = 0; tj < 4; ++tj)
                acc[ti][tj] = __builtin_amdgcn_mfma_f32_16x16x32_bf16(
                    af[ti], bf[tj], acc[ti][tj], 0, 0, 0);
        __syncthreads();
    }

#pragma unroll
    for (int ti = 0; ti < 4; ++ti) {
#pragma unroll
        for (int tj = 0; tj < 4; ++tj) {
            const int mrow = j0 + wj * 64 + tj * 16 + l15;
            const int abase = i0 + wi * 64 + ti * 16 + quad * 4;
            f32x4 v = acc[ti][tj];
            float4 o; o.x = v[0]; o.y = v[1]; o.z = v[2]; o.w = v[3];
            *(float4*)(logits + (size_t)mrow * 1024 + abase) = o;
        }
    }
}

// ---------------------------------------------------------------- softmax+mom
// One workgroup per (b,e) row: softmax over precomputed logits -> sel bf16;
// momentum head (fp32 exact) -> cumprod to d_out's second region.
__global__ __launch_bounds__(256) void k_softmax_mom(
        const float* __restrict__ logits_g, const float* __restrict__ bsel,
        const float* __restrict__ x, const float* __restrict__ Wmom,
        const float* __restrict__ bmom, unsigned short* __restrict__ sel,
        float* __restrict__ momout) {
    __shared__ float xs[128];
    __shared__ float logits[1024];
    __shared__ float mvals[128];
    __shared__ float wred[4];
    __shared__ float sstat[2];
    const int tid = threadIdx.x;
    const int m = blockIdx.x;

    if (tid < 32) *(float4*)&xs[tid * 4] = *(const float4*)(x + (size_t)m * 128 + tid * 4);
    for (int a = tid; a < 1024; a += 256)
        logits[a] = logits_g[(size_t)m * 1024 + a] + bsel[a];
    __syncthreads();

    if (tid < 128) {
        const float4* w = (const float4*)(Wmom + (size_t)tid * 128);
        float acc = 0.f;
#pragma unroll
        for (int k = 0; k < 32; ++k) {
            float4 wv = w[k]; float4 xv = *(const float4*)&xs[k * 4];
            acc += wv.x * xv.x + wv.y * xv.y + wv.z * xv.z + wv.w * xv.w;
        }
        acc += bmom[tid];
        float sig = 1.f / (1.f + __expf(-acc));
        mvals[tid] = 0.2f + sig * 0.72f;      // BASE_RES + sigmoid*RES_FACTOR
    }
    __syncthreads();

    float mx = -1e30f;
    for (int a = tid; a < 1024; a += 256) mx = fmaxf(mx, logits[a]);
#pragma unroll
    for (int off = 32; off; off >>= 1) mx = fmaxf(mx, __shfl_xor(mx, off, 64));
    if ((tid & 63) == 0) wred[tid >> 6] = mx;
    __syncthreads();
    if (tid == 0) sstat[0] = fmaxf(fmaxf(wred[0], wred[1]), fmaxf(wred[2], wred[3]));
    __syncthreads();
    mx = sstat[0];

    float psum = 0.f;
    for (int a = tid; a < 1024; a += 256) {
        float e = __expf(logits[a] - mx);
        logits[a] = e;
        psum += e;
    }
#pragma unroll
    for (int off = 32; off; off >>= 1) psum += __shfl_xor(psum, off, 64);
    if ((tid & 63) == 0) wred[tid >> 6] = psum;
    __syncthreads();
    if (tid == 0) sstat[1] = wred[0] + wred[1] + wred[2] + wred[3];
    __syncthreads();
    const float inv = 1.f / sstat[1];
    for (int a = tid; a < 1024; a += 256)
        sel[(size_t)m * 1024 + a] = f2bf(logits[a] * inv);

    if (tid == 0) {
        float p = 1.f;
        for (int f = 0; f < 128; ++f) {
            p *= (mvals[f] + 1e-12f);
            momout[(size_t)m * 128 + f] = p;
        }
    }
}

// ---------------------------------------------------------------- transpose
// atoms fp32 [1024][32768] -> atomsT bf16 [32768][1024] via 64x64 LDS tile.
__global__ __launch_bounds__(256) void k_transpose(
        const float* __restrict__ atoms, unsigned short* __restrict__ atomsT) {
    __shared__ float t[64][65];
    const int tid = threadIdx.x;
    const int s0 = blockIdx.x * 64;
    const int a0 = blockIdx.y * 64;

    {
        const int r0 = tid >> 4;
        const int c4 = (tid & 15) * 4;
        for (int rr = r0; rr < 64; rr += 16) {
            float4 v = *(const float4*)(atoms + (size_t)(a0 + rr) * 32768 + s0 + c4);
            t[rr][c4] = v.x; t[rr][c4 + 1] = v.y; t[rr][c4 + 2] = v.z; t[rr][c4 + 3] = v.w;
        }
    }
    __syncthreads();
    {
        const int sl = tid >> 2;
        const int seg = (tid & 3) * 16;
        unsigned short* dst = atomsT + (size_t)(s0 + sl) * 1024 + a0 + seg;
        unsigned pk[8];
#pragma unroll
        for (int i = 0; i < 16; i += 2) {
            unsigned short h0 = f2bf(t[seg + i][sl]);
            unsigned short h1 = f2bf(t[seg + i + 1][sl]);
            pk[i >> 1] = (unsigned)h0 | ((unsigned)h1 << 16);
        }
        uint4 q0; q0.x = pk[0]; q0.y = pk[1]; q0.z = pk[2]; q0.w = pk[3];
        uint4 q1; q1.x = pk[4]; q1.y = pk[5]; q1.z = pk[6]; q1.w = pk[7];
        *(uint4*)(dst) = q0;
        *(uint4*)(dst + 8) = q1;
    }
}

// ---------------------------------------------------------------- main gemm
// res[m][s] = sum_a sel[m][a] * atomsT[s][a]. 128x128 tile, BK=32.
// XCD-aware linear grid: the 8 m-tiles sharing an s-tile get bids that are
// congruent mod 8 (same XCD under round-robin) AND within a 64-bid window
// (co-resident) -> atomsT tile fetched once per XCD L2.
__global__ __launch_bounds__(256) void k_gemm(
        const unsigned short* __restrict__ A, const unsigned short* __restrict__ Bm,
        unsigned short* __restrict__ res) {
    __shared__ __align__(16) unsigned short lA[128 * 32];
    __shared__ __align__(16) unsigned short lB[128 * 32];
    const int tid = threadIdx.x;
    const int wave = tid >> 6;
    const int lane = tid & 63;
    const int l15 = lane & 15, quad = lane >> 4;
    const int bid = blockIdx.x;
    const int s_tile = ((bid >> 6) << 3) | (bid & 7);   // 0..255
    const int m_tile = (bid >> 3) & 7;                  // 0..7
    const int j0 = m_tile * 128;   // m (sel rows)
    const int i0 = s_tile * 128;   // s (atomsT rows)
    const int wi = wave >> 1, wj = wave & 1;
    const int rsel = lane >> 2;
    const int koff = (lane & 3) * 8;

    f32x4 acc[4][4] = {};

    for (int kt = 0; kt < 32; ++kt) {
        const int kbase = kt * 32;
#pragma unroll
        for (int c = 0; c < 2; ++c) {
            const int row = c * 64 + wave * 16 + rsel;
            const unsigned short* ga = A + (size_t)(i0 + row) * 1024 + kbase + koff;
            const unsigned short* gb = Bm + (size_t)(j0 + row) * 1024 + kbase + koff;
            unsigned short* la = lA + (c * 64 + wave * 16) * 32;
            unsigned short* lb = lB + (c * 64 + wave * 16) * 32;
            __builtin_amdgcn_global_load_lds((GV*)ga, (LV*)la, 16, 0, 0);
            __builtin_amdgcn_global_load_lds((GV*)gb, (LV*)lb, 16, 0, 0);
        }
        __syncthreads();

        short8 af[4], bf[4];
#pragma unroll
        for (int ti = 0; ti < 4; ++ti)
            af[ti] = *(const short8*)(lA + (wi * 64 + ti * 16 + l15) * 32 + quad * 8);
#pragma unroll
        for (int tj = 0; tj < 4; ++tj)
            bf[tj] = *(const short8*)(lB + (wj * 64 + tj * 16 + l15) * 32 + quad * 8);
#pragma unroll
        for (int ti = 0; ti < 4; ++ti)
#pragma unroll
            for (int tj = 0; tj < 4; ++tj)
                acc[ti][tj] = __builtin_amdgcn_mfma_f32_16x16x32_bf16(
                    af[ti], bf[tj], acc[ti][tj], 0, 0, 0);
        __syncthreads();
    }

#pragma unroll
    for (int ti = 0; ti < 4; ++ti) {
#pragma unroll
        for (int tj = 0; tj < 4; ++tj) {
            const int mrow = j0 + wj * 64 + tj * 16 + l15;
            const int sbase = i0 + wi * 64 + ti * 16 + quad * 4;
            f32x4 v = acc[ti][tj];
            uint2 q;
            q.x = (unsigned)f2bf(v[0]) | ((unsigned)f2bf(v[1]) << 16);
            q.y = (unsigned)f2bf(v[2]) | ((unsigned)f2bf(v[3]) << 16);
            *(uint2*)(res + (size_t)mrow * 32768 + sbase) = q;
        }
    }
}

// ---------------------------------------------------------------- finalize
__global__ __launch_bounds__(256) void k_final(
        const unsigned short* __restrict__ res, const float* __restrict__ mom,
        float* __restrict__ out) {
    __shared__ __align__(16) unsigned short row[32768];
    __shared__ float hann[512];
    __shared__ float scale[128];
    const int tid = threadIdx.x;
    const int m = blockIdx.x;

#pragma unroll
    for (int j = 0; j < 16; ++j)
        *(uint4*)(row + j * 2048 + tid * 8) =
            *(const uint4*)(res + (size_t)m * 32768 + j * 2048 + tid * 8);
    for (int i = tid; i < 512; i += 256)
        hann[i] = 0.5f * (1.f - cosf(6.283185307179586f * (float)i / 512.f));
    __syncthreads();

    const int wave = tid >> 6, lane = tid & 63;
    for (int f = wave; f < 128; f += 4) {
        float s = 0.f;
#pragma unroll
        for (int jj = 0; jj < 4; ++jj) {
            const int i = jj * 128 + lane * 2;
            const int idx = f * 256 + i;
            float v0 = 0.f, v1 = 0.f;
            if (idx < 32768) {
                unsigned pr = *(const unsigned*)&row[idx];
                v0 = bf2f((unsigned short)pr);
                v1 = bf2f((unsigned short)(pr >> 16));
            }
            float w0 = v0 * hann[i], w1 = v1 * hann[i + 1];
            s += w0 * w0 + w1 * w1;
        }
#pragma unroll
        for (int off = 32; off; off >>= 1) s += __shfl_xor(s, off, 64);
        if (lane == 0) scale[f] = mom[(size_t)m * 128 + f] / (sqrtf(s) + 1e-8f);
    }
    __syncthreads();

#pragma unroll 4
    for (int j = 0; j < 32; ++j) {
        const int s0 = j * 1024 + tid * 4;
        const int f1 = s0 >> 8, i1 = s0 & 255;
        const float sc1 = scale[f1];
        const float sc0 = f1 ? scale[f1 - 1] : 0.f;
        uint2 rp = *(const uint2*)&row[s0];
        float4 o;
        o.x = bf2f((unsigned short)rp.x)         * (hann[i1]     * sc1 + hann[i1 + 256] * sc0);
        o.y = bf2f((unsigned short)(rp.x >> 16)) * (hann[i1 + 1] * sc1 + hann[i1 + 257] * sc0);
        o.z = bf2f((unsigned short)rp.y)         * (hann[i1 + 2] * sc1 + hann[i1 + 258] * sc0);
        o.w = bf2f((unsigned short)(rp.y >> 16)) * (hann[i1 + 3] * sc1 + hann[i1 + 259] * sc0);
        *(float4*)(out + (size_t)m * 32768 + s0) = o;
    }
}

extern "C" void kernel_launch(void* const* d_in, const int* in_sizes, int n_in,
                              void* d_out, int out_size, void* d_ws, size_t ws_size,
                              hipStream_t stream) {
    const float* x     = (const float*)d_in[0];
    const float* Wsel  = (const float*)d_in[1];
    const float* bsel  = (const float*)d_in[2];
    const float* Wmom  = (const float*)d_in[3];
    const float* bmom  = (const float*)d_in[4];
    const float* atoms = (const float*)d_in[5];

    float* out    = (float*)d_out;
    float* momout = out + (size_t)1024 * 32768;

    unsigned char* ws = (unsigned char*)d_ws;
    unsigned short* atomsT = (unsigned short*)(ws);                 // 64 MB
    unsigned short* sel    = (unsigned short*)(ws + 67108864);      //  2 MB
    unsigned short* res    = (unsigned short*)(ws + 69206016);      // 64 MB
    // transient head buffers inside the (not-yet-written) res region:
    float*          logits = (float*)res;                           // 4 MB
    unsigned short* xbf    = (unsigned short*)(ws + 69206016 + 4194304);
    unsigned short* wbf    = (unsigned short*)(ws + 69206016 + 4194304 + 262144);

    k_convert<<<128, 256, 0, stream>>>(x, Wsel, xbf, wbf);
    k_head_gemm<<<dim3(8, 8), 256, 0, stream>>>(wbf, xbf, logits);
    k_softmax_mom<<<1024, 256, 0, stream>>>(logits, bsel, x, Wmom, bmom, sel, momout);
    k_transpose<<<dim3(512, 16), 256, 0, stream>>>(atoms, atomsT);
    k_gemm<<<2048, 256, 0, stream>>>(atomsT, sel, res);
    k_final<<<1024, 256, 0, stream>>>(res, momout, out);
}

// Round 3
// 402.932 us; speedup vs baseline: 1.2051x; 1.0250x over previous
//
#include <hip/hip_runtime.h>

// RecurrentResonanceModel on MI355X.
// Pipeline:
//   k_convert    : x, W_sel fp32 -> bf16; Wmom -> WmomT fp32 (transposed)
//   k_head_gemm  : logits[m][a] = x[m][:] . Wsel[a][:]  (MFMA, f32 out)
//   k_softmax_mom: softmax(logits)+bsel -> sel bf16; mom head fp32 (exact,
//                  lane-coalesced via WmomT)
//   k_transpose  : atoms fp32 [A][S] -> bf16 [S][A]
//   k_gemm       : res[m][s] = sel[m][:] . atomsT[s][:] (MFMA, XCD-swizzled,
//                  LDS-coalesced epilogue stores)
//   k_final      : single-pass chunk norms (P0/P1) + scale + overlap-add,
//                  no row staging -> high occupancy
//
// Sizes: M=1024 (B*E), L=128, A=1024, S=32768, F=128, W=512, HOP=256.
// d_out = [ out (1024*32768 f32) | mom (1024*128 f32) ]
// d_ws  = [ atomsT bf16 64MB | sel bf16 2MB | res bf16 64MB ]
//         logits f32 (4MB) + xbf + wbf + WmomT live inside the res region and
//         are fully consumed before k_gemm overwrites it.

typedef __attribute__((ext_vector_type(8))) short short8;
typedef __attribute__((ext_vector_type(4))) float f32x4;

typedef __attribute__((address_space(1))) void GV;
typedef __attribute__((address_space(3))) void LV;

__device__ __forceinline__ unsigned short f2bf(float f) {
    union { float f; unsigned u; } c; c.f = f;
    unsigned u = c.u;
    u = (u + 0x7FFFu + ((u >> 16) & 1u)) >> 16;   // RNE
    return (unsigned short)u;
}
__device__ __forceinline__ float bf2f(unsigned short h) {
    union { unsigned u; float f; } c; c.u = ((unsigned)h) << 16; return c.f;
}

// ---------------------------------------------------------------- convert
// x (131072 f32) -> xbf, Wsel (131072 f32) -> wbf. Blocks 0..7 additionally
// transpose Wmom (128x128 f32) -> WmomT (fp32 exact, for coalesced mom dot).
__global__ __launch_bounds__(256) void k_convert(
        const float* __restrict__ x, const float* __restrict__ Wsel,
        const float* __restrict__ Wmom,
        unsigned short* __restrict__ xbf, unsigned short* __restrict__ wbf,
        float* __restrict__ WmomT) {
    const int i = (blockIdx.x * 256 + threadIdx.x) * 4;
    {
        float4 v = *(const float4*)(x + i);
        uint2 q;
        q.x = (unsigned)f2bf(v.x) | ((unsigned)f2bf(v.y) << 16);
        q.y = (unsigned)f2bf(v.z) | ((unsigned)f2bf(v.w) << 16);
        *(uint2*)(xbf + i) = q;
    }
    {
        float4 v = *(const float4*)(Wsel + i);
        uint2 q;
        q.x = (unsigned)f2bf(v.x) | ((unsigned)f2bf(v.y) << 16);
        q.y = (unsigned)f2bf(v.z) | ((unsigned)f2bf(v.w) << 16);
        *(uint2*)(wbf + i) = q;
    }
    if (blockIdx.x < 8) {
        const int f  = blockIdx.x * 16 + (threadIdx.x >> 4);   // 0..127
        const int kc = (threadIdx.x & 15) * 8;                 // 0..120
        float4 a = *(const float4*)(Wmom + (size_t)f * 128 + kc);
        float4 b = *(const float4*)(Wmom + (size_t)f * 128 + kc + 4);
        WmomT[(kc + 0) * 128 + f] = a.x; WmomT[(kc + 1) * 128 + f] = a.y;
        WmomT[(kc + 2) * 128 + f] = a.z; WmomT[(kc + 3) * 128 + f] = a.w;
        WmomT[(kc + 4) * 128 + f] = b.x; WmomT[(kc + 5) * 128 + f] = b.y;
        WmomT[(kc + 6) * 128 + f] = b.z; WmomT[(kc + 7) * 128 + f] = b.w;
    }
}

// ---------------------------------------------------------------- head gemm
// logits[m][a] = sum_k xbf[m][k] * wbf[a][k], K=128. grid (8,8).
__global__ __launch_bounds__(256) void k_head_gemm(
        const unsigned short* __restrict__ A, const unsigned short* __restrict__ Bm,
        float* __restrict__ logits) {
    __shared__ __align__(16) unsigned short lA[128 * 32];
    __shared__ __align__(16) unsigned short lB[128 * 32];
    const int tid = threadIdx.x;
    const int wave = tid >> 6;
    const int lane = tid & 63;
    const int l15 = lane & 15, quad = lane >> 4;
    const int i0 = blockIdx.x * 128;   // a (Wsel rows)
    const int j0 = blockIdx.y * 128;   // m (x rows)
    const int wi = wave >> 1, wj = wave & 1;
    const int rsel = lane >> 2;
    const int koff = (lane & 3) * 8;

    f32x4 acc[4][4] = {};

    for (int kt = 0; kt < 4; ++kt) {
        const int kbase = kt * 32;
#pragma unroll
        for (int c = 0; c < 2; ++c) {
            const int row = c * 64 + wave * 16 + rsel;
            const unsigned short* ga = A + (size_t)(i0 + row) * 128 + kbase + koff;
            const unsigned short* gb = Bm + (size_t)(j0 + row) * 128 + kbase + koff;
            unsigned short* la = lA + (c * 64 + wave * 16) * 32;
            unsigned short* lb = lB + (c * 64 + wave * 16) * 32;
            __builtin_amdgcn_global_load_lds((GV*)ga, (LV*)la, 16, 0, 0);
            __builtin_amdgcn_global_load_lds((GV*)gb, (LV*)lb, 16, 0, 0);
        }
        __syncthreads();

        short8 af[4], bf[4];
#pragma unroll
        for (int ti = 0; ti < 4; ++ti)
            af[ti] = *(const short8*)(lA + (wi * 64 + ti * 16 + l15) * 32 + quad * 8);
#pragma unroll
        for (int tj = 0; tj < 4; ++tj)
            bf[tj] = *(const short8*)(lB + (wj * 64 + tj * 16 + l15) * 32 + quad * 8);
#pragma unroll
        for (int ti = 0; ti < 4; ++ti)
#pragma unroll
            for (int tj = 0; tj < 4; ++tj)
                acc[ti][tj] = __builtin_amdgcn_mfma_f32_16x16x32_bf16(
                    af[ti], bf[tj], acc[ti][tj], 0, 0, 0);
        __syncthreads();
    }

#pragma unroll
    for (int ti = 0; ti < 4; ++ti) {
#pragma unroll
        for (int tj = 0; tj < 4; ++tj) {
            const int mrow = j0 + wj * 64 + tj * 16 + l15;
            const int abase = i0 + wi * 64 + ti * 16 + quad * 4;
            f32x4 v = acc[ti][tj];
            float4 o; o.x = v[0]; o.y = v[1]; o.z = v[2]; o.w = v[3];
            *(float4*)(logits + (size_t)mrow * 1024 + abase) = o;
        }
    }
}

// ---------------------------------------------------------------- softmax+mom
__global__ __launch_bounds__(256) void k_softmax_mom(
        const float* __restrict__ logits_g, const float* __restrict__ bsel,
        const float* __restrict__ x, const float* __restrict__ WmomT,
        const float* __restrict__ bmom, unsigned short* __restrict__ sel,
        float* __restrict__ momout) {
    __shared__ float xs[128];
    __shared__ float logits[1024];
    __shared__ float mvals[128];
    __shared__ float wred[4];
    __shared__ float sstat[2];
    const int tid = threadIdx.x;
    const int m = blockIdx.x;

    if (tid < 32) *(float4*)&xs[tid * 4] = *(const float4*)(x + (size_t)m * 128 + tid * 4);
    for (int a = tid; a < 1024; a += 256)
        logits[a] = logits_g[(size_t)m * 1024 + a] + bsel[a];
    __syncthreads();

    if (tid < 128) {
        float acc = bmom[tid];
#pragma unroll 8
        for (int k = 0; k < 128; ++k)
            acc += xs[k] * WmomT[k * 128 + tid];     // lane-coalesced
        float sig = 1.f / (1.f + __expf(-acc));
        mvals[tid] = 0.2f + sig * 0.72f;      // BASE_RES + sigmoid*RES_FACTOR
    }

    float mx = -1e30f;
    for (int a = tid; a < 1024; a += 256) mx = fmaxf(mx, logits[a]);
#pragma unroll
    for (int off = 32; off; off >>= 1) mx = fmaxf(mx, __shfl_xor(mx, off, 64));
    if ((tid & 63) == 0) wred[tid >> 6] = mx;
    __syncthreads();
    if (tid == 0) sstat[0] = fmaxf(fmaxf(wred[0], wred[1]), fmaxf(wred[2], wred[3]));
    __syncthreads();
    mx = sstat[0];

    float psum = 0.f;
    for (int a = tid; a < 1024; a += 256) {
        float e = __expf(logits[a] - mx);
        logits[a] = e;
        psum += e;
    }
#pragma unroll
    for (int off = 32; off; off >>= 1) psum += __shfl_xor(psum, off, 64);
    if ((tid & 63) == 0) wred[tid >> 6] = psum;
    __syncthreads();
    if (tid == 0) sstat[1] = wred[0] + wred[1] + wred[2] + wred[3];
    __syncthreads();
    const float inv = 1.f / sstat[1];
    for (int a = tid; a < 1024; a += 256)
        sel[(size_t)m * 1024 + a] = f2bf(logits[a] * inv);

    if (tid == 0) {
        float p = 1.f;
        for (int f = 0; f < 128; ++f) {
            p *= (mvals[f] + 1e-12f);
            momout[(size_t)m * 128 + f] = p;
        }
    }
}

// ---------------------------------------------------------------- transpose
// atoms fp32 [1024][32768] -> atomsT bf16 [32768][1024] via 64x64 LDS tile.
__global__ __launch_bounds__(256) void k_transpose(
        const float* __restrict__ atoms, unsigned short* __restrict__ atomsT) {
    __shared__ float t[64][65];
    const int tid = threadIdx.x;
    const int s0 = blockIdx.x * 64;
    const int a0 = blockIdx.y * 64;

    {
        const int r0 = tid >> 4;
        const int c4 = (tid & 15) * 4;
        for (int rr = r0; rr < 64; rr += 16) {
            float4 v = *(const float4*)(atoms + (size_t)(a0 + rr) * 32768 + s0 + c4);
            t[rr][c4] = v.x; t[rr][c4 + 1] = v.y; t[rr][c4 + 2] = v.z; t[rr][c4 + 3] = v.w;
        }
    }
    __syncthreads();
    {
        const int sl = tid >> 2;
        const int seg = (tid & 3) * 16;
        unsigned short* dst = atomsT + (size_t)(s0 + sl) * 1024 + a0 + seg;
        unsigned pk[8];
#pragma unroll
        for (int i = 0; i < 16; i += 2) {
            unsigned short h0 = f2bf(t[seg + i][sl]);
            unsigned short h1 = f2bf(t[seg + i + 1][sl]);
            pk[i >> 1] = (unsigned)h0 | ((unsigned)h1 << 16);
        }
        uint4 q0; q0.x = pk[0]; q0.y = pk[1]; q0.z = pk[2]; q0.w = pk[3];
        uint4 q1; q1.x = pk[4]; q1.y = pk[5]; q1.z = pk[6]; q1.w = pk[7];
        *(uint4*)(dst) = q0;
        *(uint4*)(dst + 8) = q1;
    }
}

// ---------------------------------------------------------------- main gemm
// res[m][s] = sum_a sel[m][a] * atomsT[s][a]. 128x128 tile, BK=32.
// XCD-aware linear grid (s-tile shared by 8 m-tiles on one XCD).
// Epilogue goes through LDS so global stores fill full cache lines.
__global__ __launch_bounds__(256) void k_gemm(
        const unsigned short* __restrict__ A, const unsigned short* __restrict__ Bm,
        unsigned short* __restrict__ res) {
    __shared__ __align__(16) unsigned short buf[17408];  // K-loop: lA|lB (16 KB); epilogue: 128x136 tile
    unsigned short* lA = buf;
    unsigned short* lB = buf + 4096;
    const int tid = threadIdx.x;
    const int wave = tid >> 6;
    const int lane = tid & 63;
    const int l15 = lane & 15, quad = lane >> 4;
    const int bid = blockIdx.x;
    const int s_tile = ((bid >> 6) << 3) | (bid & 7);   // 0..255
    const int m_tile = (bid >> 3) & 7;                  // 0..7
    const int j0 = m_tile * 128;   // m (sel rows)
    const int i0 = s_tile * 128;   // s (atomsT rows)
    const int wi = wave >> 1, wj = wave & 1;
    const int rsel = lane >> 2;
    const int koff = (lane & 3) * 8;

    f32x4 acc[4][4] = {};

    for (int kt = 0; kt < 32; ++kt) {
        const int kbase = kt * 32;
#pragma unroll
        for (int c = 0; c < 2; ++c) {
            const int row = c * 64 + wave * 16 + rsel;
            const unsigned short* ga = A + (size_t)(i0 + row) * 1024 + kbase + koff;
            const unsigned short* gb = Bm + (size_t)(j0 + row) * 1024 + kbase + koff;
            unsigned short* la = lA + (c * 64 + wave * 16) * 32;
            unsigned short* lb = lB + (c * 64 + wave * 16) * 32;
            __builtin_amdgcn_global_load_lds((GV*)ga, (LV*)la, 16, 0, 0);
            __builtin_amdgcn_global_load_lds((GV*)gb, (LV*)lb, 16, 0, 0);
        }
        __syncthreads();

        short8 af[4], bf[4];
#pragma unroll
        for (int ti = 0; ti < 4; ++ti)
            af[ti] = *(const short8*)(lA + (wi * 64 + ti * 16 + l15) * 32 + quad * 8);
#pragma unroll
        for (int tj = 0; tj < 4; ++tj)
            bf[tj] = *(const short8*)(lB + (wj * 64 + tj * 16 + l15) * 32 + quad * 8);
#pragma unroll
        for (int ti = 0; ti < 4; ++ti)
#pragma unroll
            for (int tj = 0; tj < 4; ++tj)
                acc[ti][tj] = __builtin_amdgcn_mfma_f32_16x16x32_bf16(
                    af[ti], bf[tj], acc[ti][tj], 0, 0, 0);
        __syncthreads();
    }

    // Epilogue: acc -> LDS [128 m][136 (s, padded)] bf16, then row-coalesced
    // global stores that fill whole 128-B lines.
#pragma unroll
    for (int ti = 0; ti < 4; ++ti) {
#pragma unroll
        for (int tj = 0; tj < 4; ++tj) {
            const int mloc = wj * 64 + tj * 16 + l15;
            const int sloc = wi * 64 + ti * 16 + quad * 4;
            f32x4 v = acc[ti][tj];
            uint2 q;
            q.x = (unsigned)f2bf(v[0]) | ((unsigned)f2bf(v[1]) << 16);
            q.y = (unsigned)f2bf(v[2]) | ((unsigned)f2bf(v[3]) << 16);
            *(uint2*)(buf + mloc * 136 + sloc) = q;
        }
    }
    __syncthreads();
    {
        const int r = tid >> 1;          // 0..127 (m within tile)
        const int h = tid & 1;           // half-row (64 shorts)
        unsigned short* grow = res + (size_t)(j0 + r) * 32768 + i0 + h * 64;
        const unsigned short* lrow = buf + r * 136 + h * 64;
#pragma unroll
        for (int j = 0; j < 8; ++j)
            *(uint4*)(grow + j * 8) = *(const uint4*)(lrow + j * 8);
    }
}

// ---------------------------------------------------------------- finalize
// One block per row, NO row staging (tiny LDS -> high occupancy).
// Pass A: per-256-sample-chunk partial norms P0 (hann first half) and P1
// (hann second half); norm^2[f] = P0[f] + P1[f+1] (chunk 128 = zero pad).
// Pass B: re-read row, scale with hann x momentum, write fp32.
__global__ __launch_bounds__(256) void k_final(
        const unsigned short* __restrict__ res, const float* __restrict__ mom,
        float* __restrict__ out) {
    __shared__ float hann[512];
    __shared__ float P0[128];
    __shared__ float P1[128];
    __shared__ float scl[129];          // scl[0]=0, scl[f+1]=mom/norm
    const int tid = threadIdx.x;
    const int m = blockIdx.x;
    const unsigned short* row = res + (size_t)m * 32768;

    hann[tid]       = 0.5f * (1.f - cosf(6.283185307179586f * (float)tid / 512.f));
    hann[tid + 256] = 0.5f * (1.f - cosf(6.283185307179586f * (float)(tid + 256) / 512.f));
    if (tid == 0) scl[0] = 0.f;
    __syncthreads();

    const int wave = tid >> 6, lane = tid & 63;
    const int ih = (lane & 31) * 8;     // within-chunk offset
    for (int cp = wave; cp < 64; cp += 4) {   // chunk pair: chunks 2cp, 2cp+1
        const unsigned short* p = row + cp * 512 + lane * 8;
        uint4 q = *(const uint4*)p;
        float s0 = 0.f, s1 = 0.f;
        const unsigned w[4] = {q.x, q.y, q.z, q.w};
#pragma unroll
        for (int j = 0; j < 4; ++j) {
            float v0 = bf2f((unsigned short)w[j]);
            float v1 = bf2f((unsigned short)(w[j] >> 16));
            float a0 = v0 * hann[ih + j * 2],       a1 = v1 * hann[ih + j * 2 + 1];
            float b0 = v0 * hann[256 + ih + j * 2], b1 = v1 * hann[256 + ih + j * 2 + 1];
            s0 += a0 * a0 + a1 * a1;
            s1 += b0 * b0 + b1 * b1;
        }
#pragma unroll
        for (int off = 1; off <= 16; off <<= 1) {     // reduce within 32-lane half
            s0 += __shfl_xor(s0, off, 64);
            s1 += __shfl_xor(s1, off, 64);
        }
        if ((lane & 31) == 0) {
            const int c = 2 * cp + (lane >> 5);
            P0[c] = s0; P1[c] = s1;
        }
    }
    __syncthreads();
    if (tid < 128) {
        const float n2 = P0[tid] + ((tid < 127) ? P1[tid + 1] : 0.f);
        scl[tid + 1] = mom[(size_t)m * 128 + tid] / (sqrtf(n2) + 1e-8f);
    }
    __syncthreads();

#pragma unroll 4
    for (int j = 0; j < 32; ++j) {
        const int s0 = j * 1024 + tid * 4;
        const int f1 = s0 >> 8, i1 = s0 & 255;
        const float sc1 = scl[f1 + 1];
        const float sc0 = scl[f1];
        uint2 rp = *(const uint2*)(row + s0);
        float4 o;
        o.x = bf2f((unsigned short)rp.x)         * (hann[i1]     * sc1 + hann[i1 + 256] * sc0);
        o.y = bf2f((unsigned short)(rp.x >> 16)) * (hann[i1 + 1] * sc1 + hann[i1 + 257] * sc0);
        o.z = bf2f((unsigned short)rp.y)         * (hann[i1 + 2] * sc1 + hann[i1 + 258] * sc0);
        o.w = bf2f((unsigned short)(rp.y >> 16)) * (hann[i1 + 3] * sc1 + hann[i1 + 259] * sc0);
        *(float4*)(out + (size_t)m * 32768 + s0) = o;
    }
}

extern "C" void kernel_launch(void* const* d_in, const int* in_sizes, int n_in,
                              void* d_out, int out_size, void* d_ws, size_t ws_size,
                              hipStream_t stream) {
    const float* x     = (const float*)d_in[0];
    const float* Wsel  = (const float*)d_in[1];
    const float* bsel  = (const float*)d_in[2];
    const float* Wmom  = (const float*)d_in[3];
    const float* bmom  = (const float*)d_in[4];
    const float* atoms = (const float*)d_in[5];

    float* out    = (float*)d_out;
    float* momout = out + (size_t)1024 * 32768;

    unsigned char* ws = (unsigned char*)d_ws;
    unsigned short* atomsT = (unsigned short*)(ws);                 // 64 MB
    unsigned short* sel    = (unsigned short*)(ws + 67108864);      //  2 MB
    unsigned short* res    = (unsigned short*)(ws + 69206016);      // 64 MB
    // transient head buffers inside the (not-yet-written) res region:
    float*          logits = (float*)res;                           // 4 MB
    unsigned short* xbf    = (unsigned short*)(ws + 69206016 + 4194304);
    unsigned short* wbf    = (unsigned short*)(ws + 69206016 + 4194304 + 262144);
    float*          WmomT  = (float*)(ws + 69206016 + 4194304 + 524288);

    k_convert<<<128, 256, 0, stream>>>(x, Wsel, Wmom, xbf, wbf, WmomT);
    k_head_gemm<<<dim3(8, 8), 256, 0, stream>>>(wbf, xbf, logits);
    k_softmax_mom<<<1024, 256, 0, stream>>>(logits, bsel, x, WmomT, bmom, sel, momout);
    k_transpose<<<dim3(512, 16), 256, 0, stream>>>(atoms, atomsT);
    k_gemm<<<2048, 256, 0, stream>>>(atomsT, sel, res);
    k_final<<<1024, 256, 0, stream>>>(res, momout, out);
}